// Round 5
// baseline (724.672 us; speedup 1.0000x reference)
//
#include <hip/hip_runtime.h>

#define S 2048
#define D 64
#define BH 32
#define CHUNK 128
#define NCH (S / CHUNK)
#define MTILE 64

typedef __attribute__((ext_vector_type(8))) short bfrag;
typedef __attribute__((ext_vector_type(4))) float f32x4;
typedef __attribute__((ext_vector_type(2))) unsigned int u32x2;
typedef __attribute__((ext_vector_type(8))) unsigned short u16x8;

__device__ __forceinline__ unsigned short f2bf(float f) {
    unsigned int u = __builtin_bit_cast(unsigned int, f);
    u += 0x7fffu + ((u >> 16) & 1u);
    return (unsigned short)(u >> 16);
}
__device__ __forceinline__ ushort4 f2bf4(float4 f) {
    ushort4 u;
    u.x = f2bf(f.x); u.y = f2bf(f.y); u.z = f2bf(f.z); u.w = f2bf(f.w);
    return u;
}
__device__ __forceinline__ void gl_lds16(const void* g, void* l) {
    __builtin_amdgcn_global_load_lds(
        (const __attribute__((address_space(1))) unsigned int*)g,
        (__attribute__((address_space(3))) unsigned int*)l, 16, 0, 0);
}

// XCD-aware 1D-grid decode: wgid%8 == bh%8 -> each XCD owns 4 bh (L2 locality).
__device__ __forceinline__ void decode_block(int w, int& bh, int& r0) {
    const int r = w & 7, bx = (w >> 3) & 31, g = w >> 8;
    bh = g * 8 + r;
    r0 = bx * MTILE;
}

// ---------------- prepass kernels ----------------

__global__ void mask_detect_kernel(const unsigned int* __restrict__ m, int* __restrict__ flag) {
    __shared__ int any;
    if (threadIdx.x == 0) any = 0;
    __syncthreads();
    unsigned int v0 = m[threadIdx.x];
    unsigned int v1 = m[threadIdx.x + 256];
    unsigned int v2 = m[threadIdx.x + 512];
    unsigned int v3 = m[threadIdx.x + 768];
    if (v0 > 1u || v1 > 1u || v2 > 1u || v3 > 1u) any = 1;
    __syncthreads();
    if (threadIdx.x == 0) *flag = any;
}

// Q (pre-scaled by 1/8) and K f32 -> bf16, same layout. 2048 blocks x 256.
__global__ void conv_qk_kernel(const float* __restrict__ q, const float* __restrict__ k,
                               unsigned short* __restrict__ qbf, unsigned short* __restrict__ kbf) {
    const size_t i8 = ((size_t)blockIdx.x * 256 + threadIdx.x) * 8;
    {
        float4 a = *(const float4*)&q[i8];
        float4 b = *(const float4*)&q[i8 + 4];
        a.x *= 0.125f; a.y *= 0.125f; a.z *= 0.125f; a.w *= 0.125f;
        b.x *= 0.125f; b.y *= 0.125f; b.z *= 0.125f; b.w *= 0.125f;
        union { u16x8 v; ushort4 h[2]; } u;
        u.h[0] = f2bf4(a); u.h[1] = f2bf4(b);
        *(u16x8*)&qbf[i8] = u.v;
    }
    {
        float4 a = *(const float4*)&k[i8];
        float4 b = *(const float4*)&k[i8 + 4];
        union { u16x8 v; ushort4 h[2]; } u;
        u.h[0] = f2bf4(a); u.h[1] = f2bf4(b);
        *(u16x8*)&kbf[i8] = u.v;
    }
}

// V [bh][k][d] f32 -> Vt [bh][d][k] bf16. 1024 blocks x 256.
__global__ void v_transpose_kernel(const float* __restrict__ v, unsigned short* __restrict__ vtbf) {
    __shared__ unsigned short Ts[64][72];
    const int t = threadIdx.x;
    const int bh = blockIdx.x >> 5;
    const int k0 = (blockIdx.x & 31) * 64;
    {
        const int kr = t >> 2, c0 = (t & 3) * 16;
        const float* src = &v[((size_t)bh * S + k0 + kr) * D + c0];
#pragma unroll
        for (int i = 0; i < 4; ++i) {
            float4 f = *(const float4*)&src[i * 4];
            *(ushort4*)&Ts[kr][c0 + i * 4] = f2bf4(f);
        }
    }
    __syncthreads();
    {
        const int d = t >> 2, kq = (t & 3) * 16;
        union { u16x8 v8; unsigned short e[8]; } u0, u1;
#pragma unroll
        for (int i = 0; i < 8; ++i) u0.e[i] = Ts[kq + i][d];
#pragma unroll
        for (int i = 0; i < 8; ++i) u1.e[i] = Ts[kq + 8 + i][d];
        unsigned short* dst = &vtbf[(size_t)bh * D * S + (size_t)d * S + k0 + kq];
        *(u16x8*)&dst[0] = u0.v8;
        *(u16x8*)&dst[8] = u1.v8;
    }
}

// mask -> bits. word idx = row*64 + w. 1024 blocks x 256.
__global__ void mask_pack_kernel(const int* __restrict__ mi, const unsigned char* __restrict__ mb,
                                 const int* __restrict__ flag, unsigned int* __restrict__ mbits) {
    const int idx = blockIdx.x * 256 + threadIdx.x;
    const int row = idx >> 6, w = idx & 63;
    unsigned bits = 0;
    if (*flag) {
        const unsigned char* src = &mb[(size_t)row * S + w * 32];
#pragma unroll
        for (int i = 0; i < 8; ++i) {
            unsigned u = *(const unsigned int*)&src[i * 4] & 0x01010101u;
            unsigned nib = (u | (u >> 7) | (u >> 14) | (u >> 21)) & 0xFu;
            bits |= nib << (i * 4);
        }
    } else {
        const int* src = &mi[(size_t)row * S + w * 32];
#pragma unroll
        for (int i = 0; i < 8; ++i) {
            int4 v = *(const int4*)&src[i * 4];
            unsigned nib = (unsigned)(v.x & 1) | ((unsigned)(v.y & 1) << 1) |
                           ((unsigned)(v.z & 1) << 2) | ((unsigned)(v.w & 1) << 3);
            bits |= nib << (i * 4);
        }
    }
    mbits[idx] = bits;
}

// ---------------- Phase A: out = softmax(QK^T)·V, plus linv ----------------

__global__ __launch_bounds__(256, 2)
void attn_phaseA(const unsigned short* __restrict__ qbf,
                 const unsigned short* __restrict__ kbf,
                 const unsigned short* __restrict__ vtbf,
                 const unsigned int* __restrict__ mbits,
                 float* __restrict__ out, float* __restrict__ linv_ws) {
    // 80 KB LDS, 2 blocks/CU:
    //   K dbuf [2][128][64] bf16 (16B-chunk XOR swizzle, chunk ^= row&7)
    //   V dbuf [2][64][128] bf16 (chunk ^= d&7)
    //   P      [4 wv][16 q][128 k] bf16 (chunk ^= q&7)
    __shared__ __attribute__((aligned(16))) unsigned short smem[40960];
    const int KB[2] = {0, 8192};
    const int VB[2] = {16384, 24576};
    const int PB = 32768;

    const int t    = threadIdx.x;
    const int lane = t & 63;
    const int wv   = t >> 6;
    const int quad = lane >> 4;
    const int l16  = lane & 15;     // swapped QK^T: this lane's q-row
    int bh, r0;
    decode_block(blockIdx.x, bh, r0);
    const int bz = bh >> 4;

    const unsigned short* kbh = kbf + (size_t)bh * S * D;
    const unsigned short* vbh = vtbf + (size_t)bh * S * D;
    const unsigned int*   mrowp = mbits + ((size_t)bz * S + r0 + wv * 16 + l16) * 64;

    // per-lane staging geometry
    int kdst[4], ksrc[4], vdst[4], vsrc[4];
#pragma unroll
    for (int i = 0; i < 4; ++i) {
        const int off = wv * 4096 + i * 1024 + lane * 16;
        {   // K: [128][64] bf16, 128B rows, 8 chunks/row
            const int r = off >> 7, cch = (off >> 4) & 7, c = cch ^ (r & 7);
            kdst[i] = off >> 1;
            ksrc[i] = r * 64 + c * 8;
        }
        {   // V: [64][128] bf16, 256B rows, 16 chunks/row
            const int d = off >> 8, p = (off >> 4) & 15, c = p ^ (d & 7);
            vdst[i] = off >> 1;
            vsrc[i] = d * S + c * 8;
        }
    }

    // Q fragments (bf16, pre-scaled in prepass)
    bfrag qf[2];
    {
        const unsigned short* qrow = qbf + ((size_t)bh * S + r0 + wv * 16 + l16) * D;
        qf[0] = *(const bfrag*)&qrow[quad * 8];
        qf[1] = *(const bfrag*)&qrow[32 + quad * 8];
    }

    float lsum = 0.f;
    f32x4 acc_o[4];
#pragma unroll
    for (int n = 0; n < 4; ++n) acc_o[n] = (f32x4){0.f, 0.f, 0.f, 0.f};

    unsigned short* Pme = &smem[PB + wv * 2048];

    // prologue: prefetch chunk 0
#pragma unroll
    for (int i = 0; i < 4; ++i) {
        gl_lds16(&kbh[ksrc[i]], &smem[KB[0] + kdst[i]]);
        gl_lds16(&vbh[vsrc[i]], &smem[VB[0] + vdst[i]]);
    }

    for (int ch = 0; ch < NCH; ++ch) {
        const int b = ch & 1;
        __syncthreads();   // vmcnt drained -> chunk ch staged

        if (ch + 1 < NCH) {
            const int j1 = (ch + 1) * CHUNK;
#pragma unroll
            for (int i = 0; i < 4; ++i) {
                gl_lds16(&kbh[j1 * 64 + ksrc[i]], &smem[KB[b ^ 1] + kdst[i]]);
                gl_lds16(&vbh[j1 + vsrc[i]], &smem[VB[b ^ 1] + vdst[i]]);
            }
        }
        const uint4 mm = *(const uint4*)(mrowp + ch * 4);

        // S^T = K·Q^T: sacc[nt][rg] = S[k = nt*16+quad*4+rg][q = l16]
        const unsigned short* Kb = &smem[KB[b]];
        f32x4 sacc[8];
#pragma unroll
        for (int nt = 0; nt < 8; ++nt) sacc[nt] = (f32x4){0.f, 0.f, 0.f, 0.f};
#pragma unroll
        for (int ks = 0; ks < 2; ++ks) {
#pragma unroll
            for (int nt = 0; nt < 8; ++nt) {
                bfrag kf = *(const bfrag*)&Kb[(nt * 16 + l16) * 64 +
                                              (((ks * 4 + quad) ^ (l16 & 7)) * 8)];
                sacc[nt] = __builtin_amdgcn_mfma_f32_16x16x32_bf16(kf, qf[ks], sacc[nt], 0, 0, 0);
            }
        }

        unsigned mw[4] = {mm.x >> (quad * 4), mm.y >> (quad * 4),
                          mm.z >> (quad * 4), mm.w >> (quad * 4)};

        // exp + mask + P write (b64, swizzled, conflict-free)
#pragma unroll
        for (int nt = 0; nt < 8; ++nt) {
            float p[4];
#pragma unroll
            for (int rg = 0; rg < 4; ++rg) {
                const unsigned bit = (mw[nt >> 1] >> (((nt & 1) << 4) + rg)) & 1u;
                p[rg] = bit ? 0.f : __expf(sacc[nt][rg]);
                lsum += p[rg];
            }
            unsigned w0 = (unsigned)f2bf(p[0]) | ((unsigned)f2bf(p[1]) << 16);
            unsigned w1 = (unsigned)f2bf(p[2]) | ((unsigned)f2bf(p[3]) << 16);
            const int cch = (2 * nt + (quad >> 1)) ^ (l16 & 7);
            *(u32x2*)&Pme[l16 * 128 + cch * 8 + (quad & 1) * 4] = (u32x2){w0, w1};
        }

        // O += P·V (P wave-private)
        const unsigned short* Vb = &smem[VB[b]];
#pragma unroll
        for (int ks = 0; ks < 4; ++ks) {
            bfrag ap = *(const bfrag*)&Pme[l16 * 128 + (((4 * ks + quad) ^ (l16 & 7)) * 8)];
#pragma unroll
            for (int nt = 0; nt < 4; ++nt) {
                bfrag bv2 = *(const bfrag*)&Vb[(nt * 16 + l16) * 128 +
                                               (((ks * 4 + quad) ^ (l16 & 7)) * 8)];
                acc_o[nt] = __builtin_amdgcn_mfma_f32_16x16x32_bf16(ap, bv2, acc_o[nt], 0, 0, 0);
            }
        }
    }

    // finish row sums
    float s2 = lsum;
    s2 += __shfl_xor(s2, 16);
    s2 += __shfl_xor(s2, 32);
    const float linv_self = 1.f / s2;
    if (quad == 0) linv_ws[(size_t)bh * S + r0 + wv * 16 + l16] = linv_self;
    float lv[4];
#pragma unroll
    for (int rg = 0; rg < 4; ++rg) lv[rg] = __shfl(linv_self, quad * 4 + rg);

    // write O = acc_o / l
#pragma unroll
    for (int nt = 0; nt < 4; ++nt) {
#pragma unroll
        for (int rg = 0; rg < 4; ++rg) {
            const int row = r0 + wv * 16 + quad * 4 + rg;
            out[((size_t)bh * S + row) * D + nt * 16 + l16] = acc_o[nt][rg] * lv[rg];
        }
    }
}

// ---------------- Phase B: atten = P/l (barrier-free, K direct from L2) ----------------

__global__ __launch_bounds__(256, 3)
void attn_phaseB(const unsigned short* __restrict__ qbf,
                 const unsigned short* __restrict__ kbf,
                 const unsigned int* __restrict__ mbits,
                 const float* __restrict__ linv_ws,
                 float* __restrict__ atten) {
    __shared__ __attribute__((aligned(16))) float Tw[4][2048];   // wave-private 8KB each

    const int t    = threadIdx.x;
    const int lane = t & 63;
    const int wv   = t >> 6;
    const int quad = lane >> 4;
    const int l16  = lane & 15;
    int bh, r0;
    decode_block(blockIdx.x, bh, r0);
    const int bz = bh >> 4;

    const unsigned short* kbh = kbf + (size_t)bh * S * D;
    const unsigned int*   mrowp = mbits + ((size_t)bz * S + r0 + wv * 16 + l16) * 64;
    const float linv_self = linv_ws[(size_t)bh * S + r0 + wv * 16 + l16];

    bfrag qf[2];
    {
        const unsigned short* qrow = qbf + ((size_t)bh * S + r0 + wv * 16 + l16) * D;
        qf[0] = *(const bfrag*)&qrow[quad * 8];
        qf[1] = *(const bfrag*)&qrow[32 + quad * 8];
    }

    float* Twv = Tw[wv];

    for (int ch = 0; ch < NCH; ++ch) {
        const int j0 = ch * CHUNK;
        const uint4 mm = *(const uint4*)(mrowp + ch * 4);

        // K fragments straight from global (L2-hot via XCD swizzle)
        bfrag kf[2][8];
#pragma unroll
        for (int ks = 0; ks < 2; ++ks)
#pragma unroll
            for (int nt = 0; nt < 8; ++nt)
                kf[ks][nt] = *(const bfrag*)&kbh[(size_t)(j0 + nt * 16 + l16) * D +
                                                 ks * 32 + quad * 8];

        f32x4 sacc[8];
#pragma unroll
        for (int nt = 0; nt < 8; ++nt) sacc[nt] = (f32x4){0.f, 0.f, 0.f, 0.f};
#pragma unroll
        for (int ks = 0; ks < 2; ++ks)
#pragma unroll
            for (int nt = 0; nt < 8; ++nt)
                sacc[nt] = __builtin_amdgcn_mfma_f32_16x16x32_bf16(kf[ks][nt], qf[ks],
                                                                   sacc[nt], 0, 0, 0);

        unsigned mw[4] = {mm.x >> (quad * 4), mm.y >> (quad * 4),
                          mm.z >> (quad * 4), mm.w >> (quad * 4)};

        // swizzled wave-private f32 transpose tile
#pragma unroll
        for (int nt = 0; nt < 8; ++nt) {
            f32x4 vals;
#pragma unroll
            for (int rg = 0; rg < 4; ++rg) {
                const unsigned bit = (mw[nt >> 1] >> (((nt & 1) << 4) + rg)) & 1u;
                vals[rg] = bit ? 0.f : __expf(sacc[nt][rg]) * linv_self;
            }
            *(f32x4*)&Twv[l16 * 128 + (((nt * 4 + quad) ^ (l16 & 7)) * 4)] = vals;
        }

        // read back row-major -> 256B-contiguous nontemporal stores
#pragma unroll
        for (int rr = 0; rr < 4; ++rr) {
            const int row = rr * 4 + quad;
#pragma unroll
            for (int h = 0; h < 2; ++h) {
                const f32x4 vals = *(const f32x4*)&Twv[row * 128 +
                                                       (((h * 16 + l16) ^ (row & 7)) * 4)];
                __builtin_nontemporal_store(
                    vals, (f32x4*)&atten[((size_t)bh * S + r0 + wv * 16 + row) * S +
                                         j0 + h * 64 + l16 * 4]);
            }
        }
    }
}

extern "C" void kernel_launch(void* const* d_in, const int* in_sizes, int n_in,
                              void* d_out, int out_size, void* d_ws, size_t ws_size,
                              hipStream_t stream) {
    const float* q = (const float*)d_in[0];
    const float* k = (const float*)d_in[1];
    const float* v = (const float*)d_in[2];
    const void* mask = d_in[3];
    float* out   = (float*)d_out;
    float* atten = out + (size_t)BH * S * D;

    // workspace layout
    char* ws = (char*)d_ws;
    int* flag = (int*)ws;                                                 // 4 B
    unsigned short* qbf  = (unsigned short*)(ws + 256);                   // 8 MB
    unsigned short* kbf  = qbf + (size_t)BH * S * D;                      // 8 MB
    unsigned short* vtbf = kbf + (size_t)BH * S * D;                      // 8 MB
    unsigned int*   mbits = (unsigned int*)(vtbf + (size_t)BH * S * D);   // 1 MB
    float*          linv_ws = (float*)(mbits + (size_t)2 * S * (S / 32)); // 256 KB

    mask_detect_kernel<<<1, 256, 0, stream>>>((const unsigned int*)mask, flag);
    conv_qk_kernel<<<2048, 256, 0, stream>>>(q, k, qbf, kbf);
    v_transpose_kernel<<<1024, 256, 0, stream>>>(v, vtbf);
    mask_pack_kernel<<<1024, 256, 0, stream>>>((const int*)mask, (const unsigned char*)mask,
                                               flag, mbits);

    attn_phaseA<<<1024, 256, 0, stream>>>(qbf, kbf, vtbf, mbits, out, linv_ws);
    attn_phaseB<<<1024, 256, 0, stream>>>(qbf, kbf, mbits, linv_ws, atten);
}

// Round 6
// 658.649 us; speedup vs baseline: 1.1002x; 1.1002x over previous
//
#include <hip/hip_runtime.h>

#define S 2048
#define D 64
#define BH 32
#define CHUNK 128
#define NCH (S / CHUNK)
#define MTILE 64

typedef __attribute__((ext_vector_type(8))) short bfrag;
typedef __attribute__((ext_vector_type(4))) float f32x4;
typedef __attribute__((ext_vector_type(2))) unsigned int u32x2;
typedef __attribute__((ext_vector_type(8))) unsigned short u16x8;

__device__ __forceinline__ unsigned short f2bf(float f) {
    unsigned int u = __builtin_bit_cast(unsigned int, f);
    u += 0x7fffu + ((u >> 16) & 1u);
    return (unsigned short)(u >> 16);
}
__device__ __forceinline__ ushort4 f2bf4(float4 f) {
    ushort4 u;
    u.x = f2bf(f.x); u.y = f2bf(f.y); u.z = f2bf(f.z); u.w = f2bf(f.w);
    return u;
}
__device__ __forceinline__ void gl_lds16(const void* g, void* l) {
    __builtin_amdgcn_global_load_lds(
        (const __attribute__((address_space(1))) unsigned int*)g,
        (__attribute__((address_space(3))) unsigned int*)l, 16, 0, 0);
}

// XCD-aware 1D-grid decode: wgid%8 == bh%8 -> each XCD owns 4 bh (L2 locality).
__device__ __forceinline__ void decode_block(int w, int& bh, int& r0) {
    const int r = w & 7, bx = (w >> 3) & 31, g = w >> 8;
    bh = g * 8 + r;
    r0 = bx * MTILE;
}

// ---------------- prepass kernels ----------------

__global__ void mask_detect_kernel(const unsigned int* __restrict__ m, int* __restrict__ flag) {
    __shared__ int any;
    if (threadIdx.x == 0) any = 0;
    __syncthreads();
    unsigned int v0 = m[threadIdx.x];
    unsigned int v1 = m[threadIdx.x + 256];
    unsigned int v2 = m[threadIdx.x + 512];
    unsigned int v3 = m[threadIdx.x + 768];
    if (v0 > 1u || v1 > 1u || v2 > 1u || v3 > 1u) any = 1;
    __syncthreads();
    if (threadIdx.x == 0) *flag = any;
}

// Q (pre-scaled by 1/8) and K f32 -> bf16, same layout. 2048 blocks x 256.
__global__ void conv_qk_kernel(const float* __restrict__ q, const float* __restrict__ k,
                               unsigned short* __restrict__ qbf, unsigned short* __restrict__ kbf) {
    const size_t i8 = ((size_t)blockIdx.x * 256 + threadIdx.x) * 8;
    {
        float4 a = *(const float4*)&q[i8];
        float4 b = *(const float4*)&q[i8 + 4];
        a.x *= 0.125f; a.y *= 0.125f; a.z *= 0.125f; a.w *= 0.125f;
        b.x *= 0.125f; b.y *= 0.125f; b.z *= 0.125f; b.w *= 0.125f;
        union { u16x8 v; ushort4 h[2]; } u;
        u.h[0] = f2bf4(a); u.h[1] = f2bf4(b);
        *(u16x8*)&qbf[i8] = u.v;
    }
    {
        float4 a = *(const float4*)&k[i8];
        float4 b = *(const float4*)&k[i8 + 4];
        union { u16x8 v; ushort4 h[2]; } u;
        u.h[0] = f2bf4(a); u.h[1] = f2bf4(b);
        *(u16x8*)&kbf[i8] = u.v;
    }
}

// V [bh][k][d] f32 -> Vt [bh][d][k] bf16. 1024 blocks x 256.
__global__ void v_transpose_kernel(const float* __restrict__ v, unsigned short* __restrict__ vtbf) {
    __shared__ unsigned short Ts[64][72];
    const int t = threadIdx.x;
    const int bh = blockIdx.x >> 5;
    const int k0 = (blockIdx.x & 31) * 64;
    {
        const int kr = t >> 2, c0 = (t & 3) * 16;
        const float* src = &v[((size_t)bh * S + k0 + kr) * D + c0];
#pragma unroll
        for (int i = 0; i < 4; ++i) {
            float4 f = *(const float4*)&src[i * 4];
            *(ushort4*)&Ts[kr][c0 + i * 4] = f2bf4(f);
        }
    }
    __syncthreads();
    {
        const int d = t >> 2, kq = (t & 3) * 16;
        union { u16x8 v8; unsigned short e[8]; } u0, u1;
#pragma unroll
        for (int i = 0; i < 8; ++i) u0.e[i] = Ts[kq + i][d];
#pragma unroll
        for (int i = 0; i < 8; ++i) u1.e[i] = Ts[kq + 8 + i][d];
        unsigned short* dst = &vtbf[(size_t)bh * D * S + (size_t)d * S + k0 + kq];
        *(u16x8*)&dst[0] = u0.v8;
        *(u16x8*)&dst[8] = u1.v8;
    }
}

// mask -> bits. word idx = row*64 + w. 1024 blocks x 256.
__global__ void mask_pack_kernel(const int* __restrict__ mi, const unsigned char* __restrict__ mb,
                                 const int* __restrict__ flag, unsigned int* __restrict__ mbits) {
    const int idx = blockIdx.x * 256 + threadIdx.x;
    const int row = idx >> 6, w = idx & 63;
    unsigned bits = 0;
    if (*flag) {
        const unsigned char* src = &mb[(size_t)row * S + w * 32];
#pragma unroll
        for (int i = 0; i < 8; ++i) {
            unsigned u = *(const unsigned int*)&src[i * 4] & 0x01010101u;
            unsigned nib = (u | (u >> 7) | (u >> 14) | (u >> 21)) & 0xFu;
            bits |= nib << (i * 4);
        }
    } else {
        const int* src = &mi[(size_t)row * S + w * 32];
#pragma unroll
        for (int i = 0; i < 8; ++i) {
            int4 v = *(const int4*)&src[i * 4];
            unsigned nib = (unsigned)(v.x & 1) | ((unsigned)(v.y & 1) << 1) |
                           ((unsigned)(v.z & 1) << 2) | ((unsigned)(v.w & 1) << 3);
            bits |= nib << (i * 4);
        }
    }
    mbits[idx] = bits;
}

// ---------------- fused attention kernel ----------------

__global__ __launch_bounds__(256, 2)
void attn_mfma_kernel(const unsigned short* __restrict__ qbf,
                      const unsigned short* __restrict__ kbf,
                      const unsigned short* __restrict__ vtbf,
                      const unsigned int* __restrict__ mbits,
                      float* __restrict__ out, float* __restrict__ atten) {
    // 80 KB LDS, 2 blocks/CU:
    //   K dbuf [2][128 k][64 d] bf16 (16B-chunk XOR swizzle, chunk ^= row&7)
    //   V dbuf [2][64 d][128 k] bf16 (chunk ^= d&7)
    //   P      [4 wv][16 q][128 k] bf16 (chunk ^= q&7)
    //   Phase B: V region reused as wave-private f32 transpose buf [16][128]
    __shared__ __attribute__((aligned(16))) unsigned short smem[40960];
    const int KB[2] = {0, 8192};
    const int VB[2] = {16384, 24576};
    const int PB = 32768;

    const int t    = threadIdx.x;
    const int lane = t & 63;
    const int wv   = t >> 6;
    const int quad = lane >> 4;
    const int l16  = lane & 15;     // swapped QK^T: this lane's q-row
    int bh, r0;
    decode_block(blockIdx.x, bh, r0);
    const int bz = bh >> 4;

    const unsigned short* kbh = kbf + (size_t)bh * S * D;
    const unsigned short* vbh = vtbf + (size_t)bh * S * D;
    const unsigned int*   mrowp = mbits + ((size_t)bz * S + r0 + wv * 16 + l16) * 64;

    // per-lane staging geometry
    int kdst[4], ksrc[4], vdst[4], vsrc[4];
#pragma unroll
    for (int i = 0; i < 4; ++i) {
        const int off = wv * 4096 + i * 1024 + lane * 16;
        {   // K: [128][64] bf16, 128B rows, 8 chunks/row
            const int r = off >> 7, cch = (off >> 4) & 7, c = cch ^ (r & 7);
            kdst[i] = off >> 1;
            ksrc[i] = r * 64 + c * 8;
        }
        {   // V: [64][128] bf16, 256B rows, 16 chunks/row
            const int d = off >> 8, p = (off >> 4) & 15, c = p ^ (d & 7);
            vdst[i] = off >> 1;
            vsrc[i] = d * S + c * 8;
        }
    }

    // Q fragments (bf16, pre-scaled in prepass)
    bfrag qf[2];
    {
        const unsigned short* qrow = qbf + ((size_t)bh * S + r0 + wv * 16 + l16) * D;
        qf[0] = *(const bfrag*)&qrow[quad * 8];
        qf[1] = *(const bfrag*)&qrow[32 + quad * 8];
    }

    float lsum = 0.f;
    f32x4 acc_o[4];
#pragma unroll
    for (int n = 0; n < 4; ++n) acc_o[n] = (f32x4){0.f, 0.f, 0.f, 0.f};

    unsigned short* Pme = &smem[PB + wv * 2048];

    // ---- prologue: prefetch chunk 0 into buffer 0 ----
#pragma unroll
    for (int i = 0; i < 4; ++i) {
        gl_lds16(&kbh[ksrc[i]], &smem[KB[0] + kdst[i]]);
        gl_lds16(&vbh[vsrc[i]], &smem[VB[0] + vdst[i]]);
    }

    // =================== Phase A: row sums + O = P·V ===================
    for (int ch = 0; ch < NCH; ++ch) {
        const int b = ch & 1;
        __syncthreads();   // vmcnt drained -> chunk ch staged

        if (ch + 1 < NCH) {   // prefetch chunk ch+1 into the other buffer
            const int j1 = (ch + 1) * CHUNK;
#pragma unroll
            for (int i = 0; i < 4; ++i) {
                gl_lds16(&kbh[j1 * 64 + ksrc[i]], &smem[KB[b ^ 1] + kdst[i]]);
                gl_lds16(&vbh[j1 + vsrc[i]], &smem[VB[b ^ 1] + vdst[i]]);
            }
        }
        const uint4 mm = *(const uint4*)(mrowp + ch * 4);

        // S^T = K·Q^T: sacc[nt][rg] = S[k = nt*16+quad*4+rg][q = l16]
        const unsigned short* Kb = &smem[KB[b]];
        f32x4 sacc[8];
#pragma unroll
        for (int nt = 0; nt < 8; ++nt) sacc[nt] = (f32x4){0.f, 0.f, 0.f, 0.f};
#pragma unroll
        for (int ks = 0; ks < 2; ++ks) {
#pragma unroll
            for (int nt = 0; nt < 8; ++nt) {
                bfrag kf = *(const bfrag*)&Kb[(nt * 16 + l16) * 64 +
                                              (((ks * 4 + quad) ^ (l16 & 7)) * 8)];
                sacc[nt] = __builtin_amdgcn_mfma_f32_16x16x32_bf16(kf, qf[ks], sacc[nt], 0, 0, 0);
            }
        }

        unsigned mw[4] = {mm.x >> (quad * 4), mm.y >> (quad * 4),
                          mm.z >> (quad * 4), mm.w >> (quad * 4)};

        // exp + mask + P write (b64, swizzled, conflict-free)
#pragma unroll
        for (int nt = 0; nt < 8; ++nt) {
            float p[4];
#pragma unroll
            for (int rg = 0; rg < 4; ++rg) {
                const unsigned bit = (mw[nt >> 1] >> (((nt & 1) << 4) + rg)) & 1u;
                p[rg] = bit ? 0.f : __expf(sacc[nt][rg]);
                lsum += p[rg];
            }
            unsigned w0 = (unsigned)f2bf(p[0]) | ((unsigned)f2bf(p[1]) << 16);
            unsigned w1 = (unsigned)f2bf(p[2]) | ((unsigned)f2bf(p[3]) << 16);
            const int cch = (2 * nt + (quad >> 1)) ^ (l16 & 7);
            *(u32x2*)&Pme[l16 * 128 + cch * 8 + (quad & 1) * 4] = (u32x2){w0, w1};
        }

        // O += P·V (P wave-private: in-wave lgkm ordering suffices)
        const unsigned short* Vb = &smem[VB[b]];
#pragma unroll
        for (int ks = 0; ks < 4; ++ks) {
            bfrag ap = *(const bfrag*)&Pme[l16 * 128 + (((4 * ks + quad) ^ (l16 & 7)) * 8)];
#pragma unroll
            for (int nt = 0; nt < 4; ++nt) {
                bfrag bv2 = *(const bfrag*)&Vb[(nt * 16 + l16) * 128 +
                                               (((ks * 4 + quad) ^ (l16 & 7)) * 8)];
                acc_o[nt] = __builtin_amdgcn_mfma_f32_16x16x32_bf16(ap, bv2, acc_o[nt], 0, 0, 0);
            }
        }
    }

    // ---- finish row sums ----
    float s2 = lsum;
    s2 += __shfl_xor(s2, 16);
    s2 += __shfl_xor(s2, 32);
    const float linv_self = 1.f / s2;
    float lv[4];
#pragma unroll
    for (int rg = 0; rg < 4; ++rg) lv[rg] = __shfl(linv_self, quad * 4 + rg);

    // ---- Phase B prologue: prefetch K chunk 0 (overlaps O-write) ----
#pragma unroll
    for (int i = 0; i < 4; ++i)
        gl_lds16(&kbh[ksrc[i]], &smem[KB[0] + kdst[i]]);

    // ---- write O = acc_o / l (nontemporal; keep L2 for K/V) ----
#pragma unroll
    for (int nt = 0; nt < 4; ++nt) {
#pragma unroll
        for (int rg = 0; rg < 4; ++rg) {
            const int row = r0 + wv * 16 + quad * 4 + rg;
            __builtin_nontemporal_store(
                acc_o[nt][rg] * lv[rg],
                &out[((size_t)bh * S + row) * D + nt * 16 + l16]);
        }
    }

    // =================== Phase B: recompute S^T, write atten = P/l ===================
    float* Twv = reinterpret_cast<float*>(&smem[VB[0]]) + wv * 2048;  // wave-private [16][128] f32
    for (int ch = 0; ch < NCH; ++ch) {
        const int b = ch & 1;
        const int j0 = ch * CHUNK;
        __syncthreads();

        if (ch + 1 < NCH) {
            const int j1 = (ch + 1) * CHUNK;
#pragma unroll
            for (int i = 0; i < 4; ++i)
                gl_lds16(&kbh[j1 * 64 + ksrc[i]], &smem[KB[b ^ 1] + kdst[i]]);
        }
        const uint4 mm = *(const uint4*)(mrowp + ch * 4);

        const unsigned short* Kb = &smem[KB[b]];
        f32x4 sacc[8];
#pragma unroll
        for (int nt = 0; nt < 8; ++nt) sacc[nt] = (f32x4){0.f, 0.f, 0.f, 0.f};
#pragma unroll
        for (int ks = 0; ks < 2; ++ks) {
#pragma unroll
            for (int nt = 0; nt < 8; ++nt) {
                bfrag kf = *(const bfrag*)&Kb[(nt * 16 + l16) * 64 +
                                              (((ks * 4 + quad) ^ (l16 & 7)) * 8)];
                sacc[nt] = __builtin_amdgcn_mfma_f32_16x16x32_bf16(kf, qf[ks], sacc[nt], 0, 0, 0);
            }
        }

        unsigned mw[4] = {mm.x >> (quad * 4), mm.y >> (quad * 4),
                          mm.z >> (quad * 4), mm.w >> (quad * 4)};

        // write swizzled f32 transpose tile (wave-private)
#pragma unroll
        for (int nt = 0; nt < 8; ++nt) {
            f32x4 vals;
#pragma unroll
            for (int rg = 0; rg < 4; ++rg) {
                const unsigned bit = (mw[nt >> 1] >> (((nt & 1) << 4) + rg)) & 1u;
                vals[rg] = bit ? 0.f : __expf(sacc[nt][rg]) * linv_self;
            }
            *(f32x4*)&Twv[l16 * 128 + (((nt * 4 + quad) ^ (l16 & 7)) * 4)] = vals;
        }

        // read back row-major -> 256B-contiguous nontemporal stores
#pragma unroll
        for (int rr = 0; rr < 4; ++rr) {
            const int row = rr * 4 + quad;
#pragma unroll
            for (int h = 0; h < 2; ++h) {
                const f32x4 vals = *(const f32x4*)&Twv[row * 128 +
                                                       (((h * 16 + l16) ^ (row & 7)) * 4)];
                __builtin_nontemporal_store(
                    vals, (f32x4*)&atten[((size_t)bh * S + r0 + wv * 16 + row) * S +
                                         j0 + h * 64 + l16 * 4]);
            }
        }
    }
}

extern "C" void kernel_launch(void* const* d_in, const int* in_sizes, int n_in,
                              void* d_out, int out_size, void* d_ws, size_t ws_size,
                              hipStream_t stream) {
    const float* q = (const float*)d_in[0];
    const float* k = (const float*)d_in[1];
    const float* v = (const float*)d_in[2];
    const void* mask = d_in[3];
    float* out   = (float*)d_out;
    float* atten = out + (size_t)BH * S * D;

    // workspace layout
    char* ws = (char*)d_ws;
    int* flag = (int*)ws;                                                 // 4 B
    unsigned short* qbf  = (unsigned short*)(ws + 256);                   // 8 MB
    unsigned short* kbf  = qbf + (size_t)BH * S * D;                      // 8 MB
    unsigned short* vtbf = kbf + (size_t)BH * S * D;                      // 8 MB
    unsigned int*   mbits = (unsigned int*)(vtbf + (size_t)BH * S * D);   // 1 MB

    mask_detect_kernel<<<1, 256, 0, stream>>>((const unsigned int*)mask, flag);
    conv_qk_kernel<<<2048, 256, 0, stream>>>(q, k, qbf, kbf);
    v_transpose_kernel<<<1024, 256, 0, stream>>>(v, vtbf);
    mask_pack_kernel<<<1024, 256, 0, stream>>>((const int*)mask, (const unsigned char*)mask,
                                               flag, mbits);

    attn_mfma_kernel<<<1024, 256, 0, stream>>>(qbf, kbf, vtbf, mbits, out, atten);
}